// Round 4
// baseline (184.921 us; speedup 1.0000x reference)
//
#include <hip/hip_runtime.h>
#include <hip/hip_fp16.h>

#define NB 4
#define NH 12
#define DHD 64
#define LQ 512
#define LK 512
#define DM 768

typedef __attribute__((ext_vector_type(4))) _Float16 f16x4;
typedef __attribute__((ext_vector_type(8))) _Float16 f16x8;
typedef __attribute__((ext_vector_type(4))) float f32x4;

// ---------------------------------------------------------------------------
// Kernel 0: LayerNorm of the 3x64 relation tables. lnK pre-scaled by 8 to
// compensate the 1/8 folded into Q at projection time.
// ---------------------------------------------------------------------------
__global__ __launch_bounds__(64) void prep_ln_kernel(
    const float* __restrict__ dpk, const float* __restrict__ dpv,
    const float* __restrict__ gk, const float* __restrict__ bk,
    const float* __restrict__ gv, const float* __restrict__ bv,
    float* __restrict__ lnK, float* __restrict__ lnV)
{
    int lane = threadIdx.x;
    for (int r = 0; r < 3; ++r) {
        {
            float x = dpk[r * DHD + lane];
            float s = x;
            #pragma unroll
            for (int o = 1; o < 64; o <<= 1) s += __shfl_xor(s, o);
            float mu = s * (1.0f / 64.0f);
            float d = x - mu;
            float v = d * d;
            #pragma unroll
            for (int o = 1; o < 64; o <<= 1) v += __shfl_xor(v, o);
            lnK[r * DHD + lane] =
                (d * rsqrtf(v * (1.0f / 64.0f) + 1e-5f) * gk[lane] + bk[lane]) * 8.0f;
        }
        {
            float x = dpv[r * DHD + lane];
            float s = x;
            #pragma unroll
            for (int o = 1; o < 64; o <<= 1) s += __shfl_xor(s, o);
            float mu = s * (1.0f / 64.0f);
            float d = x - mu;
            float v = d * d;
            #pragma unroll
            for (int o = 1; o < 64; o <<= 1) v += __shfl_xor(v, o);
            lnV[r * DHD + lane] = d * rsqrtf(v * (1.0f / 64.0f) + 1e-5f) * gv[lane] + bv[lane];
        }
    }
}

// ---------------------------------------------------------------------------
// Kernel 1: QKV projection, fp16 MFMA. Tile 128x128, K-step 64, 12 iters,
// 4 waves in 2x2 each doing 4x4 MFMA 16x16x32 tiles (32 MFMA/wave/iter).
// Q scaled by 1/8 in the epilogue fma. Q,K out [B,H,L,64]; V out [B,H,64,L].
// Epilogue: 128x128 halves = 2048 f16x8 stores = 256 thr x 8 iters (p<8!).
// ---------------------------------------------------------------------------
__global__ __launch_bounds__(256) void qkv_mfma(
    const float* __restrict__ hidden, const float* __restrict__ context,
    const float* __restrict__ Wq, const float* __restrict__ bq,
    const float* __restrict__ Wk, const float* __restrict__ bk,
    const float* __restrict__ Wv, const float* __restrict__ bv,
    _Float16* __restrict__ Qh, _Float16* __restrict__ Kh,
    _Float16* __restrict__ VTh)
{
    __shared__ __align__(16) char smem[36864];
    _Float16 (*sA)[72]  = (_Float16(*)[72])smem;             // 128x72 = 18432 B
    _Float16 (*sBT)[72] = (_Float16(*)[72])(smem + 18432);   // 128x72 = 18432 B
    _Float16 (*sC)[136] = (_Float16(*)[136])smem;            // 128x136 = 34816 B

    const int t = threadIdx.x;
    const int w = t >> 6, lane = t & 63, g = lane >> 4, c16 = lane & 15;
    const int wm = w >> 1, wn = w & 1;
    const int mat = blockIdx.y / 6;         // 0=Q,1=K,2=V
    const int nt0 = blockIdx.y % 6;         // 128-col tile (2 heads)
    const float* X    = (mat == 0) ? hidden : context;
    const float* W    = (mat == 0) ? Wq : (mat == 1) ? Wk : Wv;
    const float* bias = (mat == 0) ? bq : (mat == 1) ? bk : bv;
    const int m0 = blockIdx.x * 128, n0 = nt0 * 128;
    const int head0 = nt0 * 2;

    f32x4 acc[4][4];
    #pragma unroll
    for (int mt = 0; mt < 4; ++mt)
        #pragma unroll
        for (int nt = 0; nt < 4; ++nt) acc[mt][nt] = (f32x4){0.f, 0.f, 0.f, 0.f};

    for (int kt = 0; kt < 12; ++kt) {
        __syncthreads();
        // stage A 128x64 (fp32->f16)
        #pragma unroll
        for (int p = 0; p < 8; ++p) {
            int idx = t + p * 256;
            int row = idx >> 4, c4 = idx & 15;
            float4 xv = *(const float4*)&X[(size_t)(m0 + row) * DM + kt * 64 + c4 * 4];
            f16x4 hv = { (_Float16)xv.x, (_Float16)xv.y, (_Float16)xv.z, (_Float16)xv.w };
            *(f16x4*)&sA[row][c4 * 4] = hv;
        }
        // stage B 64x128 transposed -> sBT[n][k]
        #pragma unroll
        for (int p = 0; p < 8; ++p) {
            int idx = t + p * 256;
            int kk = idx >> 5, c4 = idx & 31;
            float4 wv = *(const float4*)&W[(size_t)(kt * 64 + kk) * DM + n0 + c4 * 4];
            sBT[c4 * 4 + 0][kk] = (_Float16)wv.x;
            sBT[c4 * 4 + 1][kk] = (_Float16)wv.y;
            sBT[c4 * 4 + 2][kk] = (_Float16)wv.z;
            sBT[c4 * 4 + 3][kk] = (_Float16)wv.w;
        }
        __syncthreads();
        #pragma unroll
        for (int kh = 0; kh < 2; ++kh) {
            f16x8 af[4], bf[4];
            #pragma unroll
            for (int mt = 0; mt < 4; ++mt)
                af[mt] = *(const f16x8*)&sA[wm * 64 + mt * 16 + c16][kh * 32 + 8 * g];
            #pragma unroll
            for (int nt = 0; nt < 4; ++nt)
                bf[nt] = *(const f16x8*)&sBT[wn * 64 + nt * 16 + c16][kh * 32 + 8 * g];
            #pragma unroll
            for (int mt = 0; mt < 4; ++mt)
                #pragma unroll
                for (int nt = 0; nt < 4; ++nt)
                    acc[mt][nt] = __builtin_amdgcn_mfma_f32_16x16x32_f16(
                        af[mt], bf[nt], acc[mt][nt], 0, 0, 0);
        }
    }

    const float sc = (mat == 0) ? 0.125f : 1.0f;
    float bb[4];
    #pragma unroll
    for (int nt = 0; nt < 4; ++nt)
        bb[nt] = bias[n0 + wn * 64 + nt * 16 + c16] * sc;
    __syncthreads();

    if (mat < 2) {
        #pragma unroll
        for (int mt = 0; mt < 4; ++mt)
            #pragma unroll
            for (int nt = 0; nt < 4; ++nt)
                #pragma unroll
                for (int r = 0; r < 4; ++r)
                    sC[wm * 64 + mt * 16 + 4 * g + r][wn * 64 + nt * 16 + c16] =
                        (_Float16)(acc[mt][nt][r] * sc + bb[nt]);
        __syncthreads();
        _Float16* dst = (mat == 0) ? Qh : Kh;
        #pragma unroll
        for (int p = 0; p < 8; ++p) {
            int idx = t + p * 256;
            int row = idx >> 4, cg = idx & 15;
            int hl = cg >> 3, d8 = cg & 7;
            int m = m0 + row, bbat = m >> 9, l = m & 511;
            *(f16x8*)&dst[((size_t)(bbat * NH + head0 + hl) * LQ + l) * DHD + d8 * 8] =
                *(const f16x8*)&sC[row][cg * 8];
        }
    } else {
        #pragma unroll
        for (int mt = 0; mt < 4; ++mt)
            #pragma unroll
            for (int nt = 0; nt < 4; ++nt)
                #pragma unroll
                for (int r = 0; r < 4; ++r)
                    sC[wn * 64 + nt * 16 + c16][wm * 64 + mt * 16 + 4 * g + r] =
                        (_Float16)(acc[mt][nt][r] + bb[nt]);
        __syncthreads();
        int bbat = m0 >> 9, l0 = m0 & 511;
        #pragma unroll
        for (int p = 0; p < 8; ++p) {
            int idx = t + p * 256;
            int n = idx >> 4, cg = idx & 15;
            *(f16x8*)&VTh[((size_t)(bbat * NH + head0 + (n >> 6)) * DHD + (n & 63)) * LK
                          + l0 + cg * 8] = *(const f16x8*)&sC[n][cg * 8];
        }
    }
}

// ---------------------------------------------------------------------------
// Kernel 2: attention, fp16 MFMA, q-tile 32. Block = (b,h,32-q tile), 4 waves;
// wave w owns keys [w*128,+128) for QK/softmax and d-cols [w*16,+16) for PV.
// Scores stay in C-fragments; exp'd P in LDS f16; V frags reused across both
// q-groups. Scale 1/8 folded into Q; lnK pre-scaled by 8.
// ---------------------------------------------------------------------------
__global__ __launch_bounds__(256) void attn_mfma(
    const _Float16* __restrict__ Qh, const _Float16* __restrict__ Kh,
    const _Float16* __restrict__ VTh, const float* __restrict__ maskp,
    const int* __restrict__ garc, const float* __restrict__ lnK,
    const float* __restrict__ lnV, float* __restrict__ outp)
{
    __shared__ __align__(16) _Float16 sP[32][520];   // 33280 B
    __shared__ unsigned char sArc[32][512];          // 16384 B
    __shared__ float sTb[32][4];
    __shared__ float sMax[4][32];
    __shared__ float sStat[4][32][4];
    __shared__ float sFin[32][4];

    const int t = threadIdx.x;
    const int w = t >> 6, lane = t & 63, g = lane >> 4, c16 = lane & 15;
    const int bx = blockIdx.x;
    const int qt = bx & 15, h = (bx >> 4) % NH, b = bx / (16 * NH);
    const int q0 = qt * 32;
    const int kw = w * 128;

    const _Float16* Qb = Qh + ((size_t)(b * NH + h) * LQ) * DHD;
    const _Float16* Kb = Kh + ((size_t)(b * NH + h) * LK) * DHD;
    const _Float16* Vb = VTh + ((size_t)(b * NH + h) * DHD) * LK;

    // stage arc rows (32 x 512 int32 -> u8)
    const int* garcRow = garc + ((size_t)(b * LQ + q0)) * LK;
    unsigned char* sArcFlat = &sArc[0][0];
    #pragma unroll
    for (int p = 0; p < 16; ++p) {
        int idx = t + p * 256;
        int4 a4 = *(const int4*)&garcRow[idx * 4];
        uchar4 u = { (unsigned char)a4.x, (unsigned char)a4.y,
                     (unsigned char)a4.z, (unsigned char)a4.w };
        *(uchar4*)&sArcFlat[idx * 4] = u;
    }
    // tb[q][r] = q . lnK[r] (lnK pre-scaled x8; Q carries 1/8)
    if (t < 192) {
        int q = t / 6, rem = t % 6, rr = rem >> 1, part = rem & 1;
        float a = 0.f;
        const _Float16* qrow = Qb + (q0 + q) * DHD;
        #pragma unroll
        for (int d0 = 0; d0 < 32; ++d0) {
            int d = part * 32 + d0;
            a += (float)qrow[d] * lnK[rr * 64 + d];
        }
        a += __shfl_xor(a, 1);
        if (part == 0) sTb[q][rr] = a;
    }
    // Q fragments for both 16-row groups
    f16x8 qa[2][2];
    #pragma unroll
    for (int qg = 0; qg < 2; ++qg) {
        qa[qg][0] = *(const f16x8*)&Qb[(q0 + 16 * qg + c16) * DHD + 8 * g];
        qa[qg][1] = *(const f16x8*)&Qb[(q0 + 16 * qg + c16) * DHD + 32 + 8 * g];
    }
    __syncthreads();

    // QK^T + fixup; scores stay in registers
    f32x4 c[8][2];
    int aPack[8][2];
    float rm[2][4];
    #pragma unroll
    for (int qg = 0; qg < 2; ++qg)
        #pragma unroll
        for (int r = 0; r < 4; ++r) rm[qg][r] = -1e30f;
    #pragma unroll
    for (int tt = 0; tt < 8; ++tt) {
        int kg = kw + tt * 16 + c16;
        f16x8 kb0 = *(const f16x8*)&Kb[kg * DHD + 8 * g];
        f16x8 kb1 = *(const f16x8*)&Kb[kg * DHD + 32 + 8 * g];
        float mv = maskp[b * LK + kg];
        #pragma unroll
        for (int qg = 0; qg < 2; ++qg) {
            f32x4 s = (f32x4){0.f, 0.f, 0.f, 0.f};
            s = __builtin_amdgcn_mfma_f32_16x16x32_f16(qa[qg][0], kb0, s, 0, 0, 0);
            s = __builtin_amdgcn_mfma_f32_16x16x32_f16(qa[qg][1], kb1, s, 0, 0, 0);
            int ap = 0;
            #pragma unroll
            for (int r = 0; r < 4; ++r) {
                int qrow = 16 * qg + 4 * g + r;
                int a = sArc[qrow][kg];
                ap |= a << (8 * r);
                float sv = s[r] + sTb[qrow][a] + mv;
                s[r] = sv;
                rm[qg][r] = fmaxf(rm[qg][r], sv);
            }
            c[tt][qg] = s;
            aPack[tt][qg] = ap;
        }
    }

    // row max across the 16 key-lanes, then cross-wave
    #pragma unroll
    for (int qg = 0; qg < 2; ++qg)
        #pragma unroll
        for (int r = 0; r < 4; ++r) {
            float m = rm[qg][r];
            m = fmaxf(m, __shfl_xor(m, 1));
            m = fmaxf(m, __shfl_xor(m, 2));
            m = fmaxf(m, __shfl_xor(m, 4));
            m = fmaxf(m, __shfl_xor(m, 8));
            rm[qg][r] = m;
        }
    if (c16 == 0)
        #pragma unroll
        for (int qg = 0; qg < 2; ++qg)
            #pragma unroll
            for (int r = 0; r < 4; ++r) sMax[w][16 * qg + 4 * g + r] = rm[qg][r];
    __syncthreads();
    float Mr[2][4];
    #pragma unroll
    for (int qg = 0; qg < 2; ++qg)
        #pragma unroll
        for (int r = 0; r < 4; ++r) {
            int q = 16 * qg + 4 * g + r;
            Mr[qg][r] = fmaxf(fmaxf(sMax[0][q], sMax[1][q]),
                              fmaxf(sMax[2][q], sMax[3][q]));
        }

    // exp, sums + arc-bucket sums, P -> LDS f16
    float rs[2][4], b0s[2][4], b1s[2][4], b2s[2][4];
    #pragma unroll
    for (int qg = 0; qg < 2; ++qg)
        #pragma unroll
        for (int r = 0; r < 4; ++r) {
            rs[qg][r] = 0.f; b0s[qg][r] = 0.f; b1s[qg][r] = 0.f; b2s[qg][r] = 0.f;
        }
    #pragma unroll
    for (int tt = 0; tt < 8; ++tt) {
        int kg = kw + tt * 16 + c16;
        #pragma unroll
        for (int qg = 0; qg < 2; ++qg)
            #pragma unroll
            for (int r = 0; r < 4; ++r) {
                float e = __expf(c[tt][qg][r] - Mr[qg][r]);
                int a = (aPack[tt][qg] >> (8 * r)) & 255;
                rs[qg][r] += e;
                b0s[qg][r] += (a == 0) ? e : 0.f;
                b1s[qg][r] += (a == 1) ? e : 0.f;
                b2s[qg][r] += (a == 2) ? e : 0.f;
                sP[16 * qg + 4 * g + r][kg] = (_Float16)e;
            }
    }
    #pragma unroll
    for (int qg = 0; qg < 2; ++qg)
        #pragma unroll
        for (int r = 0; r < 4; ++r) {
            #pragma unroll
            for (int o = 1; o < 16; o <<= 1) {
                rs[qg][r]  += __shfl_xor(rs[qg][r], o);
                b0s[qg][r] += __shfl_xor(b0s[qg][r], o);
                b1s[qg][r] += __shfl_xor(b1s[qg][r], o);
                b2s[qg][r] += __shfl_xor(b2s[qg][r], o);
            }
        }
    if (c16 == 0)
        #pragma unroll
        for (int qg = 0; qg < 2; ++qg)
            #pragma unroll
            for (int r = 0; r < 4; ++r) {
                float4 v = make_float4(rs[qg][r], b0s[qg][r], b1s[qg][r], b2s[qg][r]);
                *(float4*)&sStat[w][16 * qg + 4 * g + r][0] = v;
            }
    __syncthreads();   // sP + sStat visible
    if (t < 32) {
        float4 tot = make_float4(0.f, 0.f, 0.f, 0.f);
        #pragma unroll
        for (int ww = 0; ww < 4; ++ww) {
            float4 v = *(const float4*)&sStat[ww][t][0];
            tot.x += v.x; tot.y += v.y; tot.z += v.z; tot.w += v.w;
        }
        sFin[t][0] = 1.0f / tot.x;
        sFin[t][1] = tot.y; sFin[t][2] = tot.z; sFin[t][3] = tot.w;
    }

    // PV: A from sP, B from transposed V (global); V frag shared across qg
    f32x4 o[2] = {(f32x4){0.f, 0.f, 0.f, 0.f}, (f32x4){0.f, 0.f, 0.f, 0.f}};
    const _Float16* vrow = Vb + (size_t)(w * 16 + c16) * LK;
    #pragma unroll
    for (int ktile = 0; ktile < 16; ++ktile) {
        f16x8 vb = *(const f16x8*)&vrow[ktile * 32 + 8 * g];
        #pragma unroll
        for (int qg = 0; qg < 2; ++qg) {
            f16x8 pa = *(const f16x8*)&sP[16 * qg + c16][ktile * 32 + 8 * g];
            o[qg] = __builtin_amdgcn_mfma_f32_16x16x32_f16(pa, vb, o[qg], 0, 0, 0);
        }
    }
    __syncthreads();   // sFin visible

    // epilogue: rank-3 lnV correction + normalize, fp32 store
    int d = w * 16 + c16;
    float lv0 = lnV[d], lv1 = lnV[64 + d], lv2 = lnV[128 + d];
    #pragma unroll
    for (int qg = 0; qg < 2; ++qg)
        #pragma unroll
        for (int r = 0; r < 4; ++r) {
            int q = 16 * qg + 4 * g + r;
            float4 st = *(const float4*)&sFin[q][0];
            float val = (o[qg][r] + st.y * lv0 + st.z * lv1 + st.w * lv2) * st.x;
            outp[((size_t)(b * LQ + q0 + q)) * DM + h * DHD + d] = val;
        }
}

// ---------------------------------------------------------------------------
extern "C" void kernel_launch(void* const* d_in, const int* in_sizes, int n_in,
                              void* d_out, int out_size, void* d_ws, size_t ws_size,
                              hipStream_t stream) {
    const float* hidden  = (const float*)d_in[0];
    const float* context = (const float*)d_in[1];
    const float* mask    = (const float*)d_in[2];
    const int*   garc    = (const int*)d_in[3];
    const float* Wq = (const float*)d_in[4];
    const float* bq = (const float*)d_in[5];
    const float* Wk = (const float*)d_in[6];
    const float* bk = (const float*)d_in[7];
    const float* Wv = (const float*)d_in[8];
    const float* bv = (const float*)d_in[9];
    const float* dpk  = (const float*)d_in[10];
    const float* dpv  = (const float*)d_in[11];
    const float* lnkg = (const float*)d_in[12];
    const float* lnkb = (const float*)d_in[13];
    const float* lnvg = (const float*)d_in[14];
    const float* lnvb = (const float*)d_in[15];
    float* out = (float*)d_out;

    const size_t perT = (size_t)NB * NH * LQ * DHD;   // 1,572,864 halves
    _Float16* Qh  = (_Float16*)d_ws;
    _Float16* Kh  = Qh + perT;
    _Float16* VTh = Kh + perT;
    float* lnK = (float*)(VTh + perT);
    float* lnV = lnK + 192;

    prep_ln_kernel<<<1, 64, 0, stream>>>(dpk, dpv, lnkg, lnkb, lnvg, lnvb, lnK, lnV);
    qkv_mfma<<<dim3(16, 18), 256, 0, stream>>>(hidden, context,
                                               Wq, bq, Wk, bk, Wv, bv,
                                               Qh, Kh, VTh);
    attn_mfma<<<768, 256, 0, stream>>>(Qh, Kh, VTh, mask, garc, lnK, lnV, out);
}

// Round 5
// 143.873 us; speedup vs baseline: 1.2853x; 1.2853x over previous
//
#include <hip/hip_runtime.h>
#include <hip/hip_fp16.h>

#define NB 4
#define NH 12
#define DHD 64
#define LQ 512
#define LK 512
#define DM 768

typedef __attribute__((ext_vector_type(4))) _Float16 f16x4;
typedef __attribute__((ext_vector_type(8))) _Float16 f16x8;
typedef __attribute__((ext_vector_type(4))) float f32x4;

// ---------------------------------------------------------------------------
// Kernel 0 (prep): blocks 0..767 convert hidden+context fp32 -> Xh f16;
// blocks 768..1199 transpose+convert Wq/Wk/Wv -> WT f16 [mat][n][k];
// block 1200 does the 3x64 LayerNorm tables (lnK pre-scaled by 8).
// ---------------------------------------------------------------------------
__global__ __launch_bounds__(256) void prep_kernel(
    const float* __restrict__ hidden, const float* __restrict__ context,
    const float* __restrict__ Wq, const float* __restrict__ Wk,
    const float* __restrict__ Wv,
    const float* __restrict__ dpk, const float* __restrict__ dpv,
    const float* __restrict__ gk, const float* __restrict__ bk,
    const float* __restrict__ gv, const float* __restrict__ bv,
    _Float16* __restrict__ Xh, _Float16* __restrict__ WT,
    float* __restrict__ lnK, float* __restrict__ lnV)
{
    const int bid = blockIdx.x, t = threadIdx.x;
    if (bid < 768) {
        // X convert: 4096 elems/block; hidden = blocks 0..383, context 384..767
        size_t base = (size_t)bid * 4096;
        const float* src = (bid < 384) ? hidden : (context - 1572864);
        #pragma unroll
        for (int p = 0; p < 4; ++p) {
            size_t i = base + t * 4 + p * 1024;
            float4 xv = *(const float4*)&src[i];
            f16x4 hv = { (_Float16)xv.x, (_Float16)xv.y,
                         (_Float16)xv.z, (_Float16)xv.w };
            *(f16x4*)&Xh[i] = hv;
        }
    } else if (bid < 1200) {
        __shared__ float sT[64][65];
        int wb = bid - 768;
        int mat = wb / 144, tile = wb % 144;
        int k0 = (tile / 12) * 64, n0 = (tile % 12) * 64;
        const float* W = (mat == 0) ? Wq : (mat == 1) ? Wk : Wv;
        #pragma unroll
        for (int p = 0; p < 4; ++p) {
            int idx = t + p * 256;
            int ki = idx >> 4, nj = (idx & 15) * 4;
            float4 wv = *(const float4*)&W[(size_t)(k0 + ki) * DM + n0 + nj];
            sT[ki][nj + 0] = wv.x; sT[ki][nj + 1] = wv.y;
            sT[ki][nj + 2] = wv.z; sT[ki][nj + 3] = wv.w;
        }
        __syncthreads();
        _Float16* dst = WT + (size_t)mat * DM * DM;
        #pragma unroll
        for (int p = 0; p < 4; ++p) {
            int idx = t + p * 256;
            int nr = idx >> 4, kj = (idx & 15) * 4;
            f16x4 hv = { (_Float16)sT[kj + 0][nr], (_Float16)sT[kj + 1][nr],
                         (_Float16)sT[kj + 2][nr], (_Float16)sT[kj + 3][nr] };
            *(f16x4*)&dst[(size_t)(n0 + nr) * DM + k0 + kj] = hv;
        }
    } else if (t < 64) {
        int lane = t;
        for (int r = 0; r < 3; ++r) {
            {
                float x = dpk[r * DHD + lane];
                float s = x;
                #pragma unroll
                for (int o = 1; o < 64; o <<= 1) s += __shfl_xor(s, o);
                float mu = s * (1.0f / 64.0f);
                float d = x - mu;
                float v = d * d;
                #pragma unroll
                for (int o = 1; o < 64; o <<= 1) v += __shfl_xor(v, o);
                lnK[r * DHD + lane] =
                    (d * rsqrtf(v * (1.0f / 64.0f) + 1e-5f) * gk[lane] + bk[lane]) * 8.0f;
            }
            {
                float x = dpv[r * DHD + lane];
                float s = x;
                #pragma unroll
                for (int o = 1; o < 64; o <<= 1) s += __shfl_xor(s, o);
                float mu = s * (1.0f / 64.0f);
                float d = x - mu;
                float v = d * d;
                #pragma unroll
                for (int o = 1; o < 64; o <<= 1) v += __shfl_xor(v, o);
                lnV[r * DHD + lane] =
                    d * rsqrtf(v * (1.0f / 64.0f) + 1e-5f) * gv[lane] + bv[lane];
            }
        }
    }
}

// ---------------------------------------------------------------------------
// Kernel 1: QKV projection, all-f16 MFMA. Tile 64(M)x128(N), K-step 64,
// 12 iters, grid 32x18 = 576 blocks. 4 waves side-by-side in N; each wave:
// 4 m-tiles x 2 n-tiles x 2 k-halves = 16 MFMA/iter. Staging is pure f16x8
// copy (no transpose, no conversion) -> conflict-free.
// Q scaled 1/8 in epilogue. Q,K out [B,H,L,64]; V out [B,H,64,L].
// ---------------------------------------------------------------------------
__global__ __launch_bounds__(256) void qkv_mfma(
    const _Float16* __restrict__ Xh, const _Float16* __restrict__ WT,
    const float* __restrict__ bq, const float* __restrict__ bk,
    const float* __restrict__ bv,
    _Float16* __restrict__ Qh, _Float16* __restrict__ Kh,
    _Float16* __restrict__ VTh)
{
    __shared__ __align__(16) char smem[27648];
    _Float16 (*sA)[72]  = (_Float16(*)[72])smem;             // 64x72  =  9216 B
    _Float16 (*sB)[72]  = (_Float16(*)[72])(smem + 9216);    // 128x72 = 18432 B
    _Float16 (*sC)[136] = (_Float16(*)[136])smem;            // 64x136 = 17408 B
    _Float16 (*sCV)[72] = (_Float16(*)[72])smem;             // 128x72 = 18432 B

    const int t = threadIdx.x;
    const int w = t >> 6, lane = t & 63, g = lane >> 4, c16 = lane & 15;
    const int mat = blockIdx.y / 6, nt0 = blockIdx.y % 6;
    const int m0 = blockIdx.x * 64, n0 = nt0 * 128, head0 = nt0 * 2;
    const _Float16* X  = Xh + (mat == 0 ? 0 : (size_t)2048 * DM);
    const _Float16* Wt = WT + (size_t)mat * DM * DM;
    const float* bias  = (mat == 0) ? bq : (mat == 1) ? bk : bv;

    f32x4 acc[4][2];
    #pragma unroll
    for (int mt = 0; mt < 4; ++mt)
        #pragma unroll
        for (int nt = 0; nt < 2; ++nt) acc[mt][nt] = (f32x4){0.f, 0.f, 0.f, 0.f};

    for (int kt = 0; kt < 12; ++kt) {
        __syncthreads();
        // A: 64 rows x 64 k
        #pragma unroll
        for (int p = 0; p < 2; ++p) {
            int idx = t + p * 256;
            int row = idx >> 3, c8 = idx & 7;
            *(f16x8*)&sA[row][c8 * 8] =
                *(const f16x8*)&X[(size_t)(m0 + row) * DM + kt * 64 + c8 * 8];
        }
        // B: 128 n-rows x 64 k (already [n][k] in WT)
        #pragma unroll
        for (int p = 0; p < 4; ++p) {
            int idx = t + p * 256;
            int n = idx >> 3, c8 = idx & 7;
            *(f16x8*)&sB[n][c8 * 8] =
                *(const f16x8*)&Wt[(size_t)(n0 + n) * DM + kt * 64 + c8 * 8];
        }
        __syncthreads();
        #pragma unroll
        for (int kh = 0; kh < 2; ++kh) {
            f16x8 af[4], bf[2];
            #pragma unroll
            for (int mt = 0; mt < 4; ++mt)
                af[mt] = *(const f16x8*)&sA[mt * 16 + c16][kh * 32 + 8 * g];
            #pragma unroll
            for (int nt = 0; nt < 2; ++nt)
                bf[nt] = *(const f16x8*)&sB[w * 32 + nt * 16 + c16][kh * 32 + 8 * g];
            #pragma unroll
            for (int mt = 0; mt < 4; ++mt)
                #pragma unroll
                for (int nt = 0; nt < 2; ++nt)
                    acc[mt][nt] = __builtin_amdgcn_mfma_f32_16x16x32_f16(
                        af[mt], bf[nt], acc[mt][nt], 0, 0, 0);
        }
    }

    const float sc = (mat == 0) ? 0.125f : 1.0f;
    float bb[2];
    #pragma unroll
    for (int nt = 0; nt < 2; ++nt)
        bb[nt] = bias[n0 + w * 32 + nt * 16 + c16] * sc;
    __syncthreads();

    const int bbat = m0 >> 9, l0 = m0 & 511;
    if (mat < 2) {
        #pragma unroll
        for (int mt = 0; mt < 4; ++mt)
            #pragma unroll
            for (int nt = 0; nt < 2; ++nt)
                #pragma unroll
                for (int r = 0; r < 4; ++r)
                    sC[mt * 16 + 4 * g + r][w * 32 + nt * 16 + c16] =
                        (_Float16)(acc[mt][nt][r] * sc + bb[nt]);
        __syncthreads();
        _Float16* dst = (mat == 0) ? Qh : Kh;
        #pragma unroll
        for (int p = 0; p < 4; ++p) {
            int idx = t + p * 256;
            int row = idx >> 4, cg = idx & 15;
            int hl = cg >> 3, d8 = cg & 7;
            *(f16x8*)&dst[((size_t)(bbat * NH + head0 + hl) * LQ + l0 + row) * DHD + d8 * 8] =
                *(const f16x8*)&sC[row][cg * 8];
        }
    } else {
        #pragma unroll
        for (int mt = 0; mt < 4; ++mt)
            #pragma unroll
            for (int nt = 0; nt < 2; ++nt)
                #pragma unroll
                for (int r = 0; r < 4; ++r)
                    sCV[w * 32 + nt * 16 + c16][mt * 16 + 4 * g + r] =
                        (_Float16)(acc[mt][nt][r] + bb[nt]);
        __syncthreads();
        #pragma unroll
        for (int p = 0; p < 4; ++p) {
            int idx = t + p * 256;
            int n = idx >> 3, c8 = idx & 7;
            *(f16x8*)&VTh[((size_t)(bbat * NH + head0 + (n >> 6)) * DHD + (n & 63)) * LK
                          + l0 + c8 * 8] = *(const f16x8*)&sCV[n][c8 * 8];
        }
    }
}

// ---------------------------------------------------------------------------
// Kernel 2: attention, fp16 MFMA, q-tile 32 (unchanged from round 4).
// ---------------------------------------------------------------------------
__global__ __launch_bounds__(256) void attn_mfma(
    const _Float16* __restrict__ Qh, const _Float16* __restrict__ Kh,
    const _Float16* __restrict__ VTh, const float* __restrict__ maskp,
    const int* __restrict__ garc, const float* __restrict__ lnK,
    const float* __restrict__ lnV, float* __restrict__ outp)
{
    __shared__ __align__(16) _Float16 sP[32][520];
    __shared__ unsigned char sArc[32][512];
    __shared__ float sTb[32][4];
    __shared__ float sMax[4][32];
    __shared__ float sStat[4][32][4];
    __shared__ float sFin[32][4];

    const int t = threadIdx.x;
    const int w = t >> 6, lane = t & 63, g = lane >> 4, c16 = lane & 15;
    const int bx = blockIdx.x;
    const int qt = bx & 15, h = (bx >> 4) % NH, b = bx / (16 * NH);
    const int q0 = qt * 32;
    const int kw = w * 128;

    const _Float16* Qb = Qh + ((size_t)(b * NH + h) * LQ) * DHD;
    const _Float16* Kb = Kh + ((size_t)(b * NH + h) * LK) * DHD;
    const _Float16* Vb = VTh + ((size_t)(b * NH + h) * DHD) * LK;

    const int* garcRow = garc + ((size_t)(b * LQ + q0)) * LK;
    unsigned char* sArcFlat = &sArc[0][0];
    #pragma unroll
    for (int p = 0; p < 16; ++p) {
        int idx = t + p * 256;
        int4 a4 = *(const int4*)&garcRow[idx * 4];
        uchar4 u = { (unsigned char)a4.x, (unsigned char)a4.y,
                     (unsigned char)a4.z, (unsigned char)a4.w };
        *(uchar4*)&sArcFlat[idx * 4] = u;
    }
    if (t < 192) {
        int q = t / 6, rem = t % 6, rr = rem >> 1, part = rem & 1;
        float a = 0.f;
        const _Float16* qrow = Qb + (q0 + q) * DHD;
        #pragma unroll
        for (int d0 = 0; d0 < 32; ++d0) {
            int d = part * 32 + d0;
            a += (float)qrow[d] * lnK[rr * 64 + d];
        }
        a += __shfl_xor(a, 1);
        if (part == 0) sTb[q][rr] = a;
    }
    f16x8 qa[2][2];
    #pragma unroll
    for (int qg = 0; qg < 2; ++qg) {
        qa[qg][0] = *(const f16x8*)&Qb[(q0 + 16 * qg + c16) * DHD + 8 * g];
        qa[qg][1] = *(const f16x8*)&Qb[(q0 + 16 * qg + c16) * DHD + 32 + 8 * g];
    }
    __syncthreads();

    f32x4 c[8][2];
    int aPack[8][2];
    float rm[2][4];
    #pragma unroll
    for (int qg = 0; qg < 2; ++qg)
        #pragma unroll
        for (int r = 0; r < 4; ++r) rm[qg][r] = -1e30f;
    #pragma unroll
    for (int tt = 0; tt < 8; ++tt) {
        int kg = kw + tt * 16 + c16;
        f16x8 kb0 = *(const f16x8*)&Kb[kg * DHD + 8 * g];
        f16x8 kb1 = *(const f16x8*)&Kb[kg * DHD + 32 + 8 * g];
        float mv = maskp[b * LK + kg];
        #pragma unroll
        for (int qg = 0; qg < 2; ++qg) {
            f32x4 s = (f32x4){0.f, 0.f, 0.f, 0.f};
            s = __builtin_amdgcn_mfma_f32_16x16x32_f16(qa[qg][0], kb0, s, 0, 0, 0);
            s = __builtin_amdgcn_mfma_f32_16x16x32_f16(qa[qg][1], kb1, s, 0, 0, 0);
            int ap = 0;
            #pragma unroll
            for (int r = 0; r < 4; ++r) {
                int qrow = 16 * qg + 4 * g + r;
                int a = sArc[qrow][kg];
                ap |= a << (8 * r);
                float sv = s[r] + sTb[qrow][a] + mv;
                s[r] = sv;
                rm[qg][r] = fmaxf(rm[qg][r], sv);
            }
            c[tt][qg] = s;
            aPack[tt][qg] = ap;
        }
    }

    #pragma unroll
    for (int qg = 0; qg < 2; ++qg)
        #pragma unroll
        for (int r = 0; r < 4; ++r) {
            float m = rm[qg][r];
            m = fmaxf(m, __shfl_xor(m, 1));
            m = fmaxf(m, __shfl_xor(m, 2));
            m = fmaxf(m, __shfl_xor(m, 4));
            m = fmaxf(m, __shfl_xor(m, 8));
            rm[qg][r] = m;
        }
    if (c16 == 0)
        #pragma unroll
        for (int qg = 0; qg < 2; ++qg)
            #pragma unroll
            for (int r = 0; r < 4; ++r) sMax[w][16 * qg + 4 * g + r] = rm[qg][r];
    __syncthreads();
    float Mr[2][4];
    #pragma unroll
    for (int qg = 0; qg < 2; ++qg)
        #pragma unroll
        for (int r = 0; r < 4; ++r) {
            int q = 16 * qg + 4 * g + r;
            Mr[qg][r] = fmaxf(fmaxf(sMax[0][q], sMax[1][q]),
                              fmaxf(sMax[2][q], sMax[3][q]));
        }

    float rs[2][4], b0s[2][4], b1s[2][4], b2s[2][4];
    #pragma unroll
    for (int qg = 0; qg < 2; ++qg)
        #pragma unroll
        for (int r = 0; r < 4; ++r) {
            rs[qg][r] = 0.f; b0s[qg][r] = 0.f; b1s[qg][r] = 0.f; b2s[qg][r] = 0.f;
        }
    #pragma unroll
    for (int tt = 0; tt < 8; ++tt) {
        int kg = kw + tt * 16 + c16;
        #pragma unroll
        for (int qg = 0; qg < 2; ++qg)
            #pragma unroll
            for (int r = 0; r < 4; ++r) {
                float e = __expf(c[tt][qg][r] - Mr[qg][r]);
                int a = (aPack[tt][qg] >> (8 * r)) & 255;
                rs[qg][r] += e;
                b0s[qg][r] += (a == 0) ? e : 0.f;
                b1s[qg][r] += (a == 1) ? e : 0.f;
                b2s[qg][r] += (a == 2) ? e : 0.f;
                sP[16 * qg + 4 * g + r][kg] = (_Float16)e;
            }
    }
    #pragma unroll
    for (int qg = 0; qg < 2; ++qg)
        #pragma unroll
        for (int r = 0; r < 4; ++r) {
            #pragma unroll
            for (int o = 1; o < 16; o <<= 1) {
                rs[qg][r]  += __shfl_xor(rs[qg][r], o);
                b0s[qg][r] += __shfl_xor(b0s[qg][r], o);
                b1s[qg][r] += __shfl_xor(b1s[qg][r], o);
                b2s[qg][r] += __shfl_xor(b2s[qg][r], o);
            }
        }
    if (c16 == 0)
        #pragma unroll
        for (int qg = 0; qg < 2; ++qg)
            #pragma unroll
            for (int r = 0; r < 4; ++r) {
                float4 v = make_float4(rs[qg][r], b0s[qg][r], b1s[qg][r], b2s[qg][r]);
                *(float4*)&sStat[w][16 * qg + 4 * g + r][0] = v;
            }
    __syncthreads();
    if (t < 32) {
        float4 tot = make_float4(0.f, 0.f, 0.f, 0.f);
        #pragma unroll
        for (int ww = 0; ww < 4; ++ww) {
            float4 v = *(const float4*)&sStat[ww][t][0];
            tot.x += v.x; tot.y += v.y; tot.z += v.z; tot.w += v.w;
        }
        sFin[t][0] = 1.0f / tot.x;
        sFin[t][1] = tot.y; sFin[t][2] = tot.z; sFin[t][3] = tot.w;
    }

    f32x4 o[2] = {(f32x4){0.f, 0.f, 0.f, 0.f}, (f32x4){0.f, 0.f, 0.f, 0.f}};
    const _Float16* vrow = Vb + (size_t)(w * 16 + c16) * LK;
    #pragma unroll
    for (int ktile = 0; ktile < 16; ++ktile) {
        f16x8 vb = *(const f16x8*)&vrow[ktile * 32 + 8 * g];
        #pragma unroll
        for (int qg = 0; qg < 2; ++qg) {
            f16x8 pa = *(const f16x8*)&sP[16 * qg + c16][ktile * 32 + 8 * g];
            o[qg] = __builtin_amdgcn_mfma_f32_16x16x32_f16(pa, vb, o[qg], 0, 0, 0);
        }
    }
    __syncthreads();

    int d = w * 16 + c16;
    float lv0 = lnV[d], lv1 = lnV[64 + d], lv2 = lnV[128 + d];
    #pragma unroll
    for (int qg = 0; qg < 2; ++qg)
        #pragma unroll
        for (int r = 0; r < 4; ++r) {
            int q = 16 * qg + 4 * g + r;
            float4 st = *(const float4*)&sFin[q][0];
            float val = (o[qg][r] + st.y * lv0 + st.z * lv1 + st.w * lv2) * st.x;
            outp[((size_t)(b * LQ + q0 + q)) * DM + h * DHD + d] = val;
        }
}

// ---------------------------------------------------------------------------
extern "C" void kernel_launch(void* const* d_in, const int* in_sizes, int n_in,
                              void* d_out, int out_size, void* d_ws, size_t ws_size,
                              hipStream_t stream) {
    const float* hidden  = (const float*)d_in[0];
    const float* context = (const float*)d_in[1];
    const float* mask    = (const float*)d_in[2];
    const int*   garc    = (const int*)d_in[3];
    const float* Wq = (const float*)d_in[4];
    const float* bq = (const float*)d_in[5];
    const float* Wk = (const float*)d_in[6];
    const float* bk = (const float*)d_in[7];
    const float* Wv = (const float*)d_in[8];
    const float* bv = (const float*)d_in[9];
    const float* dpk  = (const float*)d_in[10];
    const float* dpv  = (const float*)d_in[11];
    const float* lnkg = (const float*)d_in[12];
    const float* lnkb = (const float*)d_in[13];
    const float* lnvg = (const float*)d_in[14];
    const float* lnvb = (const float*)d_in[15];
    float* out = (float*)d_out;

    const size_t perT = (size_t)NB * NH * LQ * DHD;   // 1,572,864 halves
    _Float16* Qh  = (_Float16*)d_ws;
    _Float16* Kh  = Qh + perT;
    _Float16* VTh = Kh + perT;
    _Float16* Xh  = VTh + perT;                        // 3,145,728 halves
    _Float16* WT  = Xh + (size_t)4096 * DM;            // 1,769,472 halves
    float* lnK = (float*)(WT + (size_t)3 * DM * DM);
    float* lnV = lnK + 192;

    prep_kernel<<<1201, 256, 0, stream>>>(hidden, context, Wq, Wk, Wv,
                                          dpk, dpv, lnkg, lnkb, lnvg, lnvb,
                                          Xh, WT, lnK, lnV);
    qkv_mfma<<<dim3(32, 18), 256, 0, stream>>>(Xh, WT, bq, bk, bv, Qh, Kh, VTh);
    attn_mfma<<<768, 256, 0, stream>>>(Qh, Kh, VTh, mask, garc, lnK, lnV, out);
}

// Round 7
// 140.969 us; speedup vs baseline: 1.3118x; 1.0206x over previous
//
#include <hip/hip_runtime.h>
#include <hip/hip_fp16.h>

#define NB 4
#define NH 12
#define DHD 64
#define LQ 512
#define LK 512
#define DM 768

typedef __attribute__((ext_vector_type(4))) _Float16 f16x4;
typedef __attribute__((ext_vector_type(8))) _Float16 f16x8;
typedef __attribute__((ext_vector_type(4))) float f32x4;

// ---------------------------------------------------------------------------
// Kernel 0 (prep): blocks 0..431 transpose+convert Wq/Wk/Wv -> WT f16
// [mat][n][k]; block 432 computes the 3x64 LN tables (lnK pre-scaled by 8).
// ---------------------------------------------------------------------------
__global__ __launch_bounds__(256) void prep_kernel(
    const float* __restrict__ Wq, const float* __restrict__ Wk,
    const float* __restrict__ Wv,
    const float* __restrict__ dpk, const float* __restrict__ dpv,
    const float* __restrict__ gk, const float* __restrict__ bk,
    const float* __restrict__ gv, const float* __restrict__ bv,
    _Float16* __restrict__ WT, float* __restrict__ lnK, float* __restrict__ lnV)
{
    const int bid = blockIdx.x, t = threadIdx.x;
    if (bid < 432) {
        __shared__ float sT[64][65];
        int mat = bid / 144, tile = bid % 144;
        int k0 = (tile / 12) * 64, n0 = (tile % 12) * 64;
        const float* W = (mat == 0) ? Wq : (mat == 1) ? Wk : Wv;
        #pragma unroll
        for (int p = 0; p < 4; ++p) {
            int idx = t + p * 256;
            int ki = idx >> 4, nj = (idx & 15) * 4;
            float4 wv = *(const float4*)&W[(size_t)(k0 + ki) * DM + n0 + nj];
            sT[ki][nj + 0] = wv.x; sT[ki][nj + 1] = wv.y;
            sT[ki][nj + 2] = wv.z; sT[ki][nj + 3] = wv.w;
        }
        __syncthreads();
        _Float16* dst = WT + (size_t)mat * DM * DM;
        #pragma unroll
        for (int p = 0; p < 4; ++p) {
            int idx = t + p * 256;
            int nr = idx >> 4, kj = (idx & 15) * 4;
            f16x4 hv = { (_Float16)sT[kj + 0][nr], (_Float16)sT[kj + 1][nr],
                         (_Float16)sT[kj + 2][nr], (_Float16)sT[kj + 3][nr] };
            *(f16x4*)&dst[(size_t)(n0 + nr) * DM + k0 + kj] = hv;
        }
    } else if (t < 64) {
        int lane = t;
        for (int r = 0; r < 3; ++r) {
            {
                float x = dpk[r * DHD + lane];
                float s = x;
                #pragma unroll
                for (int o = 1; o < 64; o <<= 1) s += __shfl_xor(s, o);
                float mu = s * (1.0f / 64.0f);
                float d = x - mu;
                float v = d * d;
                #pragma unroll
                for (int o = 1; o < 64; o <<= 1) v += __shfl_xor(v, o);
                lnK[r * DHD + lane] =
                    (d * rsqrtf(v * (1.0f / 64.0f) + 1e-5f) * gk[lane] + bk[lane]) * 8.0f;
            }
            {
                float x = dpv[r * DHD + lane];
                float s = x;
                #pragma unroll
                for (int o = 1; o < 64; o <<= 1) s += __shfl_xor(s, o);
                float mu = s * (1.0f / 64.0f);
                float d = x - mu;
                float v = d * d;
                #pragma unroll
                for (int o = 1; o < 64; o <<= 1) v += __shfl_xor(v, o);
                lnV[r * DHD + lane] =
                    d * rsqrtf(v * (1.0f / 64.0f) + 1e-5f) * gv[lane] + bv[lane];
            }
        }
    }
}

// ---------------------------------------------------------------------------
// Kernel 1: QKV projection, fp16 MFMA. Tile 64(M)x128(N), K-step 64,
// 12 iters, grid 32x18 = 576 blocks. A staged fp32->f16 on the fly
// (round-2/3/4-proven pattern, stride 72 = 2-way free); B is pure f16x8
// copy from WT. Q scaled 1/8 in epilogue. Q,K out [B,H,L,64]; V [B,H,64,L].
// ---------------------------------------------------------------------------
__global__ __launch_bounds__(256) void qkv_mfma(
    const float* __restrict__ hidden, const float* __restrict__ context,
    const _Float16* __restrict__ WT,
    const float* __restrict__ bq, const float* __restrict__ bk,
    const float* __restrict__ bv,
    _Float16* __restrict__ Qh, _Float16* __restrict__ Kh,
    _Float16* __restrict__ VTh)
{
    __shared__ __align__(16) char smem[27648];
    _Float16 (*sA)[72]  = (_Float16(*)[72])smem;             // 64x72  =  9216 B
    _Float16 (*sB)[72]  = (_Float16(*)[72])(smem + 9216);    // 128x72 = 18432 B
    _Float16 (*sC)[136] = (_Float16(*)[136])smem;            // 64x136 = 17408 B
    _Float16 (*sCV)[72] = (_Float16(*)[72])smem;             // 128x72 = 18432 B

    const int t = threadIdx.x;
    const int w = t >> 6, lane = t & 63, g = lane >> 4, c16 = lane & 15;
    const int mat = blockIdx.y / 6, nt0 = blockIdx.y % 6;
    const int m0 = blockIdx.x * 64, n0 = nt0 * 128, head0 = nt0 * 2;
    const float* X     = (mat == 0) ? hidden : context;
    const _Float16* Wt = WT + (size_t)mat * DM * DM;
    const float* bias  = (mat == 0) ? bq : (mat == 1) ? bk : bv;

    f32x4 acc[4][2];
    #pragma unroll
    for (int mt = 0; mt < 4; ++mt)
        #pragma unroll
        for (int nt = 0; nt < 2; ++nt) acc[mt][nt] = (f32x4){0.f, 0.f, 0.f, 0.f};

    for (int kt = 0; kt < 12; ++kt) {
        __syncthreads();
        // A: 64 rows x 64 k, fp32 -> f16 convert during staging
        #pragma unroll
        for (int p = 0; p < 4; ++p) {
            int idx = t + p * 256;
            int row = idx >> 4, c4 = idx & 15;
            float4 xv = *(const float4*)&X[(size_t)(m0 + row) * DM + kt * 64 + c4 * 4];
            f16x4 hv = { (_Float16)xv.x, (_Float16)xv.y,
                         (_Float16)xv.z, (_Float16)xv.w };
            *(f16x4*)&sA[row][c4 * 4] = hv;
        }
        // B: 128 n-rows x 64 k (already [n][k] f16 in WT)
        #pragma unroll
        for (int p = 0; p < 4; ++p) {
            int idx = t + p * 256;
            int n = idx >> 3, c8 = idx & 7;
            *(f16x8*)&sB[n][c8 * 8] =
                *(const f16x8*)&Wt[(size_t)(n0 + n) * DM + kt * 64 + c8 * 8];
        }
        __syncthreads();
        #pragma unroll
        for (int kh = 0; kh < 2; ++kh) {
            f16x8 af[4], bf[2];
            #pragma unroll
            for (int mt = 0; mt < 4; ++mt)
                af[mt] = *(const f16x8*)&sA[mt * 16 + c16][kh * 32 + 8 * g];
            #pragma unroll
            for (int nt = 0; nt < 2; ++nt)
                bf[nt] = *(const f16x8*)&sB[w * 32 + nt * 16 + c16][kh * 32 + 8 * g];
            #pragma unroll
            for (int mt = 0; mt < 4; ++mt)
                #pragma unroll
                for (int nt = 0; nt < 2; ++nt)
                    acc[mt][nt] = __builtin_amdgcn_mfma_f32_16x16x32_f16(
                        af[mt], bf[nt], acc[mt][nt], 0, 0, 0);
        }
    }

    const float sc = (mat == 0) ? 0.125f : 1.0f;
    float bb[2];
    #pragma unroll
    for (int nt = 0; nt < 2; ++nt)
        bb[nt] = bias[n0 + w * 32 + nt * 16 + c16] * sc;
    __syncthreads();

    const int bbat = m0 >> 9, l0 = m0 & 511;
    if (mat < 2) {
        #pragma unroll
        for (int mt = 0; mt < 4; ++mt)
            #pragma unroll
            for (int nt = 0; nt < 2; ++nt)
                #pragma unroll
                for (int r = 0; r < 4; ++r)
                    sC[mt * 16 + 4 * g + r][w * 32 + nt * 16 + c16] =
                        (_Float16)(acc[mt][nt][r] * sc + bb[nt]);
        __syncthreads();
        _Float16* dst = (mat == 0) ? Qh : Kh;
        #pragma unroll
        for (int p = 0; p < 4; ++p) {
            int idx = t + p * 256;
            int row = idx >> 4, cg = idx & 15;
            int hl = cg >> 3, d8 = cg & 7;
            *(f16x8*)&dst[((size_t)(bbat * NH + head0 + hl) * LQ + l0 + row) * DHD + d8 * 8] =
                *(const f16x8*)&sC[row][cg * 8];
        }
    } else {
        #pragma unroll
        for (int mt = 0; mt < 4; ++mt)
            #pragma unroll
            for (int nt = 0; nt < 2; ++nt)
                #pragma unroll
                for (int r = 0; r < 4; ++r)
                    sCV[w * 32 + nt * 16 + c16][mt * 16 + 4 * g + r] =
                        (_Float16)(acc[mt][nt][r] + bb[nt]);
        __syncthreads();
        #pragma unroll
        for (int p = 0; p < 4; ++p) {
            int idx = t + p * 256;
            int n = idx >> 3, c8 = idx & 7;
            *(f16x8*)&VTh[((size_t)(bbat * NH + head0 + (n >> 6)) * DHD + (n & 63)) * LK
                          + l0 + c8 * 8] = *(const f16x8*)&sCV[n][c8 * 8];
        }
    }
}

// ---------------------------------------------------------------------------
// Kernel 2: attention, fp16 MFMA, q-tile 32 — verbatim the round-5 passing
// version. Block = (b,h,32-q tile), 4 waves; wave w owns keys [w*128,+128)
// for QK/softmax and d-cols [w*16,+16) for PV. Scores stay in C-fragments;
// exp'd P in LDS f16; V frags reused across both q-groups.
// ---------------------------------------------------------------------------
__global__ __launch_bounds__(256) void attn_mfma(
    const _Float16* __restrict__ Qh, const _Float16* __restrict__ Kh,
    const _Float16* __restrict__ VTh, const float* __restrict__ maskp,
    const int* __restrict__ garc, const float* __restrict__ lnK,
    const float* __restrict__ lnV, float* __restrict__ outp)
{
    __shared__ __align__(16) _Float16 sP[32][520];
    __shared__ unsigned char sArc[32][512];
    __shared__ float sTb[32][4];
    __shared__ float sMax[4][32];
    __shared__ float sStat[4][32][4];
    __shared__ float sFin[32][4];

    const int t = threadIdx.x;
    const int w = t >> 6, lane = t & 63, g = lane >> 4, c16 = lane & 15;
    const int bx = blockIdx.x;
    const int qt = bx & 15, h = (bx >> 4) % NH, b = bx / (16 * NH);
    const int q0 = qt * 32;
    const int kw = w * 128;

    const _Float16* Qb = Qh + ((size_t)(b * NH + h) * LQ) * DHD;
    const _Float16* Kb = Kh + ((size_t)(b * NH + h) * LK) * DHD;
    const _Float16* Vb = VTh + ((size_t)(b * NH + h) * DHD) * LK;

    const int* garcRow = garc + ((size_t)(b * LQ + q0)) * LK;
    unsigned char* sArcFlat = &sArc[0][0];
    #pragma unroll
    for (int p = 0; p < 16; ++p) {
        int idx = t + p * 256;
        int4 a4 = *(const int4*)&garcRow[idx * 4];
        uchar4 u = { (unsigned char)a4.x, (unsigned char)a4.y,
                     (unsigned char)a4.z, (unsigned char)a4.w };
        *(uchar4*)&sArcFlat[idx * 4] = u;
    }
    if (t < 192) {
        int q = t / 6, rem = t % 6, rr = rem >> 1, part = rem & 1;
        float a = 0.f;
        const _Float16* qrow = Qb + (q0 + q) * DHD;
        #pragma unroll
        for (int d0 = 0; d0 < 32; ++d0) {
            int d = part * 32 + d0;
            a += (float)qrow[d] * lnK[rr * 64 + d];
        }
        a += __shfl_xor(a, 1);
        if (part == 0) sTb[q][rr] = a;
    }
    f16x8 qa[2][2];
    #pragma unroll
    for (int qg = 0; qg < 2; ++qg) {
        qa[qg][0] = *(const f16x8*)&Qb[(q0 + 16 * qg + c16) * DHD + 8 * g];
        qa[qg][1] = *(const f16x8*)&Qb[(q0 + 16 * qg + c16) * DHD + 32 + 8 * g];
    }
    __syncthreads();

    f32x4 c[8][2];
    int aPack[8][2];
    float rm[2][4];
    #pragma unroll
    for (int qg = 0; qg < 2; ++qg)
        #pragma unroll
        for (int r = 0; r < 4; ++r) rm[qg][r] = -1e30f;
    #pragma unroll
    for (int tt = 0; tt < 8; ++tt) {
        int kg = kw + tt * 16 + c16;
        f16x8 kb0 = *(const f16x8*)&Kb[kg * DHD + 8 * g];
        f16x8 kb1 = *(const f16x8*)&Kb[kg * DHD + 32 + 8 * g];
        float mv = maskp[b * LK + kg];
        #pragma unroll
        for (int qg = 0; qg < 2; ++qg) {
            f32x4 s = (f32x4){0.f, 0.f, 0.f, 0.f};
            s = __builtin_amdgcn_mfma_f32_16x16x32_f16(qa[qg][0], kb0, s, 0, 0, 0);
            s = __builtin_amdgcn_mfma_f32_16x16x32_f16(qa[qg][1], kb1, s, 0, 0, 0);
            int ap = 0;
            #pragma unroll
            for (int r = 0; r < 4; ++r) {
                int qrow = 16 * qg + 4 * g + r;
                int a = sArc[qrow][kg];
                ap |= a << (8 * r);
                float sv = s[r] + sTb[qrow][a] + mv;
                s[r] = sv;
                rm[qg][r] = fmaxf(rm[qg][r], sv);
            }
            c[tt][qg] = s;
            aPack[tt][qg] = ap;
        }
    }

    #pragma unroll
    for (int qg = 0; qg < 2; ++qg)
        #pragma unroll
        for (int r = 0; r < 4; ++r) {
            float m = rm[qg][r];
            m = fmaxf(m, __shfl_xor(m, 1));
            m = fmaxf(m, __shfl_xor(m, 2));
            m = fmaxf(m, __shfl_xor(m, 4));
            m = fmaxf(m, __shfl_xor(m, 8));
            rm[qg][r] = m;
        }
    if (c16 == 0)
        #pragma unroll
        for (int qg = 0; qg < 2; ++qg)
            #pragma unroll
            for (int r = 0; r < 4; ++r) sMax[w][16 * qg + 4 * g + r] = rm[qg][r];
    __syncthreads();
    float Mr[2][4];
    #pragma unroll
    for (int qg = 0; qg < 2; ++qg)
        #pragma unroll
        for (int r = 0; r < 4; ++r) {
            int q = 16 * qg + 4 * g + r;
            Mr[qg][r] = fmaxf(fmaxf(sMax[0][q], sMax[1][q]),
                              fmaxf(sMax[2][q], sMax[3][q]));
        }

    float rs[2][4], b0s[2][4], b1s[2][4], b2s[2][4];
    #pragma unroll
    for (int qg = 0; qg < 2; ++qg)
        #pragma unroll
        for (int r = 0; r < 4; ++r) {
            rs[qg][r] = 0.f; b0s[qg][r] = 0.f; b1s[qg][r] = 0.f; b2s[qg][r] = 0.f;
        }
    #pragma unroll
    for (int tt = 0; tt < 8; ++tt) {
        int kg = kw + tt * 16 + c16;
        #pragma unroll
        for (int qg = 0; qg < 2; ++qg)
            #pragma unroll
            for (int r = 0; r < 4; ++r) {
                float e = __expf(c[tt][qg][r] - Mr[qg][r]);
                int a = (aPack[tt][qg] >> (8 * r)) & 255;
                rs[qg][r] += e;
                b0s[qg][r] += (a == 0) ? e : 0.f;
                b1s[qg][r] += (a == 1) ? e : 0.f;
                b2s[qg][r] += (a == 2) ? e : 0.f;
                sP[16 * qg + 4 * g + r][kg] = (_Float16)e;
            }
    }
    #pragma unroll
    for (int qg = 0; qg < 2; ++qg)
        #pragma unroll
        for (int r = 0; r < 4; ++r) {
            #pragma unroll
            for (int o = 1; o < 16; o <<= 1) {
                rs[qg][r]  += __shfl_xor(rs[qg][r], o);
                b0s[qg][r] += __shfl_xor(b0s[qg][r], o);
                b1s[qg][r] += __shfl_xor(b1s[qg][r], o);
                b2s[qg][r] += __shfl_xor(b2s[qg][r], o);
            }
        }
    if (c16 == 0)
        #pragma unroll
        for (int qg = 0; qg < 2; ++qg)
            #pragma unroll
            for (int r = 0; r < 4; ++r) {
                float4 v = make_float4(rs[qg][r], b0s[qg][r], b1s[qg][r], b2s[qg][r]);
                *(float4*)&sStat[w][16 * qg + 4 * g + r][0] = v;
            }
    __syncthreads();
    if (t < 32) {
        float4 tot = make_float4(0.f, 0.f, 0.f, 0.f);
        #pragma unroll
        for (int ww = 0; ww < 4; ++ww) {
            float4 v = *(const float4*)&sStat[ww][t][0];
            tot.x += v.x; tot.y += v.y; tot.z += v.z; tot.w += v.w;
        }
        sFin[t][0] = 1.0f / tot.x;
        sFin[t][1] = tot.y; sFin[t][2] = tot.z; sFin[t][3] = tot.w;
    }

    f32x4 o[2] = {(f32x4){0.f, 0.f, 0.f, 0.f}, (f32x4){0.f, 0.f, 0.f, 0.f}};
    const _Float16* vrow = Vb + (size_t)(w * 16 + c16) * LK;
    #pragma unroll
    for (int ktile = 0; ktile < 16; ++ktile) {
        f16x8 vb = *(const f16x8*)&vrow[ktile * 32 + 8 * g];
        #pragma unroll
        for (int qg = 0; qg < 2; ++qg) {
            f16x8 pa = *(const f16x8*)&sP[16 * qg + c16][ktile * 32 + 8 * g];
            o[qg] = __builtin_amdgcn_mfma_f32_16x16x32_f16(pa, vb, o[qg], 0, 0, 0);
        }
    }
    __syncthreads();

    int d = w * 16 + c16;
    float lv0 = lnV[d], lv1 = lnV[64 + d], lv2 = lnV[128 + d];
    #pragma unroll
    for (int qg = 0; qg < 2; ++qg)
        #pragma unroll
        for (int r = 0; r < 4; ++r) {
            int q = 16 * qg + 4 * g + r;
            float4 st = *(const float4*)&sFin[q][0];
            float val = (o[qg][r] + st.y * lv0 + st.z * lv1 + st.w * lv2) * st.x;
            outp[((size_t)(b * LQ + q0 + q)) * DM + h * DHD + d] = val;
        }
}

// ---------------------------------------------------------------------------
extern "C" void kernel_launch(void* const* d_in, const int* in_sizes, int n_in,
                              void* d_out, int out_size, void* d_ws, size_t ws_size,
                              hipStream_t stream) {
    const float* hidden  = (const float*)d_in[0];
    const float* context = (const float*)d_in[1];
    const float* mask    = (const float*)d_in[2];
    const int*   garc    = (const int*)d_in[3];
    const float* Wq = (const float*)d_in[4];
    const float* bq = (const float*)d_in[5];
    const float* Wk = (const float*)d_in[6];
    const float* bk = (const float*)d_in[7];
    const float* Wv = (const float*)d_in[8];
    const float* bv = (const float*)d_in[9];
    const float* dpk  = (const float*)d_in[10];
    const float* dpv  = (const float*)d_in[11];
    const float* lnkg = (const float*)d_in[12];
    const float* lnkb = (const float*)d_in[13];
    const float* lnvg = (const float*)d_in[14];
    const float* lnvb = (const float*)d_in[15];
    float* out = (float*)d_out;

    const size_t perT = (size_t)NB * NH * LQ * DHD;   // 1,572,864 halves
    _Float16* Qh  = (_Float16*)d_ws;
    _Float16* Kh  = Qh + perT;
    _Float16* VTh = Kh + perT;
    _Float16* WT  = VTh + perT;                        // 3*768*768 halves
    float* lnK = (float*)(WT + (size_t)3 * DM * DM);
    float* lnV = lnK + 192;

    prep_kernel<<<433, 256, 0, stream>>>(Wq, Wk, Wv, dpk, dpv,
                                         lnkg, lnkb, lnvg, lnvb, WT, lnK, lnV);
    qkv_mfma<<<dim3(32, 18), 256, 0, stream>>>(hidden, context, WT,
                                               bq, bk, bv, Qh, Kh, VTh);
    attn_mfma<<<768, 256, 0, stream>>>(Qh, Kh, VTh, mask, garc, lnK, lnV, out);
}